// Round 11
// baseline (1478.158 us; speedup 1.0000x reference)
//
#include <hip/hip_runtime.h>

#define BB 8
#define NN 2048
#define CHUNKS (NN / 64)                 // 32
#define MAX_ITER 50

// half_iter geometry: no LDS, 512 WGs x 256 thr, 4 waves/WG, 8 rows/wave
#define HGRID 512
#define HWGS 256
#define HWPB (HGRID / BB)                // 64 WGs per batch
#define HROWS_WG (NN / HWPB)             // 32 rows per WG
#define HRPW 8                           // rows per wave

// finalize geometry (runs once; keep LDS-staged r10 form)
#define FGRID 256
#define FWGS 1024
#define FNW (FWGS / 64)                  // 16 waves
#define FWPB (FGRID / BB)                // 32
#define FROWS_WG (NN / FWPB)             // 64
#define FRPW (FROWS_WG / FNW)            // 4

// eps = 0.005; log2 domain: SCL = log2(e)/eps
constexpr float SCL       = 288.5390081777927f;
constexpr float LN2f      = 0.6931471805599453f;
constexpr float EPSf      = 0.005f;
constexpr float EPS_LOGMU = -0.03812309493079699f; // 0.005 * (-ln 2048)

__device__ __forceinline__ float fexp2(float x) { return __builtin_amdgcn_exp2f(x); }
__device__ __forceinline__ float flog2(float x) { return __builtin_amdgcn_logf(x); }

__device__ __forceinline__ int   fkey(float x) { int i = __float_as_int(x); return i >= 0 ? i : i ^ 0x7fffffff; }
__device__ __forceinline__ float funkey(int k) { return __int_as_float(k >= 0 ? k : k ^ 0x7fffffff); }

__device__ __forceinline__ float wsum(float v) {
  #pragma unroll
  for (int d = 32; d; d >>= 1) v += __shfl_xor(v, d, 64);
  return v;
}

// One-time prep: rowsPack{1,2} = {x,y,z,|p|^2}; stage2 init = {x,y,z,-qq*SCL}
// (the t=0 f-update consumes stage2 with pot==0); init 32 max slots.
__global__ __launch_bounds__(256) void pack_pts(
    const float* __restrict__ pcs1, const float* __restrict__ pcs2,
    float4* __restrict__ rp1, float4* __restrict__ rp2,
    float4* __restrict__ stage2, int* __restrict__ slots)
{
  int idx = blockIdx.x * 256 + threadIdx.x;
  if (idx < 32) slots[idx] = fkey(-3.0e38f);
  if (idx >= 2 * BB * NN) return;
  if (idx < BB * NN) {
    const float* s = pcs1 + 3 * (size_t)idx;
    float x = s[0], y = s[1], z = s[2];
    rp1[idx] = make_float4(x, y, z, fmaf(x, x, fmaf(y, y, z * z)));
  } else {
    int j = idx - BB * NN;
    const float* s = pcs2 + 3 * (size_t)j;
    float x = s[0], y = s[1], z = s[2];
    float qq = fmaf(x, x, fmaf(y, y, z * z));
    rp2[j] = make_float4(x, y, z, qq);
    stage2[j] = make_float4(x, y, z, -qq * SCL);
  }
}

// One half-iteration, LDS-free: consumers stream consumer-ready float4s
// {x,y,z,(pot_j-qq_j)*SCL} from L1/L2 (512KB total, L2-resident; producers of
// the previous dispatch wrote them). Exponent arg = (B_r - M) + X_r·q + q.w
// <= 0 by construction (M >= max_j pot_j*SCL, C >= 0). Producer emits the
// next stage array + float pot + per-batch atomicMax for the next M.
template <bool ZERO_POT>
__global__ __launch_bounds__(HWGS) void half_iter(
    const float4* __restrict__ rowsPack, const float4* __restrict__ stageCols,
    float* __restrict__ potOut, float4* __restrict__ stageOut,
    const int* __restrict__ maxInSlot, int* __restrict__ maxOutSlot,
    int* __restrict__ maxResetSlot)
{
  __shared__ float red[HWGS / 64];
  const int wg = blockIdx.x, tid = threadIdx.x;
  const int b = wg / HWPB, sub = wg % HWPB;
  const int lane = tid & 63, wv = tid >> 6;

  if (sub == 0 && tid == HWGS - 1)
    __hip_atomic_store(maxResetSlot + b, fkey(-3.0e38f),
                       __ATOMIC_RELAXED, __HIP_MEMORY_SCOPE_AGENT);

  const float M = ZERO_POT ? 0.f
      : funkey(__hip_atomic_load(maxInSlot + b, __ATOMIC_RELAXED,
                                 __HIP_MEMORY_SCOPE_AGENT)) * SCL;

  const int i0 = sub * HROWS_WG + wv * HRPW;
  const float4* R  = rowsPack + (size_t)b * NN + i0;
  const float4* ST = stageCols + (size_t)b * NN;

  float4 p[HRPW];
  float Xx[HRPW], Xy[HRPW], Xz[HRPW], Bm[HRPW], s[HRPW];
  #pragma unroll
  for (int r = 0; r < HRPW; ++r) {
    p[r] = R[r];
    Xx[r] = 2.f * SCL * p[r].x;
    Xy[r] = 2.f * SCL * p[r].y;
    Xz[r] = 2.f * SCL * p[r].z;
    Bm[r] = -SCL * p[r].w - M;
    s[r] = 0.f;
  }

  // unroll capped at 4: keeps <=4 global float4 loads in flight (full unroll
  // -> load clustering -> VGPR blowup/spill, the rounds-1..5 killer)
  #pragma unroll 4
  for (int k = 0; k < CHUNKS; ++k) {
    float4 q = ST[k * 64 + lane];
    #pragma unroll
    for (int r = 0; r < HRPW; ++r)
      s[r] += fexp2(fmaf(Xx[r], q.x, fmaf(Xy[r], q.y,
                    fmaf(Xz[r], q.z, q.w + Bm[r]))));
  }

  float wmx = -3.4e38f;
  #pragma unroll
  for (int r = 0; r < HRPW; ++r) {
    float S = wsum(s[r]);
    if (lane == 0) {
      float o = EPS_LOGMU - EPSf * LN2f * (M + flog2(fmaxf(S, 1e-37f)));
      potOut[(size_t)b * NN + i0 + r] = o;
      stageOut[(size_t)b * NN + i0 + r] =
          make_float4(p[r].x, p[r].y, p[r].z, (o - p[r].w) * SCL);
      wmx = fmaxf(wmx, o);
    }
  }
  if (lane == 0) red[wv] = wmx;
  __syncthreads();
  if (tid == 0) {
    float mx = red[0];
    #pragma unroll
    for (int w = 1; w < HWGS / 64; ++w) mx = fmaxf(mx, red[w]);
    atomicMax(maxOutSlot + b, fkey(mx));   // one far-atomic per WG
  }
}

// dist_i = N * sum_j exp2((f_i + g_j - C_ij)*SCL) * C_ij ; per-WG partial
// sums of sqrt(dist) -> partials[wg]. Runs once; LDS-staged (r10 form).
__global__ __launch_bounds__(FWGS) void emd_finalize(
    const float4* __restrict__ rowsPack, const float4* __restrict__ colsPack,
    const float* __restrict__ fArr, const float* __restrict__ gArr,
    float* __restrict__ partials)
{
  __shared__ float4 J[NN];   // {x,y,z, g_j*SCL}
  __shared__ float red[FNW];
  const int wg = blockIdx.x, tid = threadIdx.x;
  const int b = wg / FWPB, sub = wg % FWPB;
  const int lane = tid & 63, wv = tid >> 6;

  const float4* C = colsPack + (size_t)b * NN;
  const float*  G = gArr + b * NN;
  #pragma unroll
  for (int j = tid; j < NN; j += FWGS) {
    float4 q = C[j];
    q.w = G[j] * SCL;
    J[j] = q;
  }
  __syncthreads();

  const int i0 = sub * FROWS_WG + wv * FRPW;
  const float4* R = rowsPack + (size_t)b * NN;
  const float*  F = fArr + b * NN;
  float part = 0.f;
  #pragma unroll 1
  for (int r = 0; r < FRPW; ++r) {
    const int i = i0 + r;
    const float4 pq = R[i];
    const float Fi = F[i] * SCL;
    float a0 = 0.f, a1 = 0.f;
    #pragma unroll 2
    for (int k = 0; k < CHUNKS; k += 2) {
      float4 qa = J[k * 64 + lane];
      float4 qb = J[(k + 1) * 64 + lane];
      float dxa = pq.x - qa.x, dya = pq.y - qa.y, dza = pq.z - qa.z;
      float ca = fmaf(dxa, dxa, fmaf(dya, dya, dza * dza));
      a0 = fmaf(fexp2(fmaf(-SCL, ca, Fi + qa.w)), ca, a0);
      float dxb = pq.x - qb.x, dyb = pq.y - qb.y, dzb = pq.z - qb.z;
      float cb = fmaf(dxb, dxb, fmaf(dyb, dyb, dzb * dzb));
      a1 = fmaf(fexp2(fmaf(-SCL, cb, Fi + qb.w)), cb, a1);
    }
    float lacc = wsum(a0 + a1);
    if (lane == 0) part += sqrtf((float)NN * lacc + 1e-12f);
  }
  if (lane == 0) red[wv] = part;
  __syncthreads();
  if (tid == 0) {
    float sm = 0.f;
    #pragma unroll
    for (int w = 0; w < FNW; ++w) sm += red[w];
    partials[wg] = sm;
  }
}

// Deterministic FGRID-way reduction -> mean.
__global__ __launch_bounds__(FGRID) void emd_reduce(
    const float* __restrict__ partials, float* __restrict__ out)
{
  __shared__ float sb[FGRID / 64];
  const int tid = threadIdx.x;
  float v = wsum(partials[tid]);
  if ((tid & 63) == 0) sb[tid >> 6] = v;
  __syncthreads();
  if (tid == 0) {
    float sm = 0.f;
    #pragma unroll
    for (int w = 0; w < FGRID / 64; ++w) sm += sb[w];
    out[0] = sm * (1.f / 16384.f);
  }
}

extern "C" void kernel_launch(void* const* d_in, const int* in_sizes, int n_in,
                              void* d_out, int out_size, void* d_ws, size_t ws_size,
                              hipStream_t stream) {
  const float* pcs1 = (const float*)d_in[0];
  const float* pcs2 = (const float*)d_in[1];
  float* out      = (float*)d_out;
  float* fArr     = (float*)d_ws;                        // BB*NN f32 (64KB)
  float* gArr     = fArr + BB * NN;                      // BB*NN f32
  float* partials = gArr + BB * NN;                      // FGRID f32
  int*   slots    = (int*)(partials + FGRID);            // 32 ints
  int*   MF[2]    = { slots,      slots + 8  };
  int*   MG[2]    = { slots + 16, slots + 24 };
  char*  base     = (char*)d_ws + 256 * 1024;
  float4* P1r  = (float4*)(base);                        // BB*NN float4 (256KB)
  float4* P2r  = (float4*)(base + 256 * 1024);
  float4* ST1  = (float4*)(base + 512 * 1024);           // stage for pcs1-pots
  float4* ST2  = (float4*)(base + 768 * 1024);           // stage for pcs2-pots

  pack_pts<<<(2 * BB * NN + 255) / 256, 256, 0, stream>>>(pcs1, pcs2, P1r, P2r, ST2, slots);

  // t=0: f reads stage2(pot=0), writes ST1+MF[0], resets MF[1]; g reads
  // ST1/MF[0], writes ST2+MG[0], resets MG[1]. Slot written at t is read at
  // t+1, reset one dispatch after last read — always kernel-boundary ordered.
  half_iter<true ><<<HGRID, HWGS, 0, stream>>>(P1r, ST2, fArr, ST1, nullptr, MF[0], MF[1]);
  half_iter<false><<<HGRID, HWGS, 0, stream>>>(P2r, ST1, gArr, ST2, MF[0], MG[0], MG[1]);
  for (int t = 1; t < MAX_ITER; ++t) {
    const int pp = t & 1, qq = pp ^ 1;
    half_iter<false><<<HGRID, HWGS, 0, stream>>>(P1r, ST2, fArr, ST1, MG[qq], MF[pp], MF[qq]);
    half_iter<false><<<HGRID, HWGS, 0, stream>>>(P2r, ST1, gArr, ST2, MF[pp], MG[pp], MG[qq]);
  }
  emd_finalize<<<FGRID, FWGS, 0, stream>>>(P1r, P2r, fArr, gArr, partials);
  emd_reduce<<<1, FGRID, 0, stream>>>(partials, out);
}

// Round 12
// 1078.451 us; speedup vs baseline: 1.3706x; 1.3706x over previous
//
#include <hip/hip_runtime.h>

#define BB 8
#define NN 2048
#define WGS 1024
#define GRID 256
#define WG_PER_B (GRID / BB)      // 32 WGs per batch
#define ROWS_WG (NN / WG_PER_B)   // 64 rows per WG
#define NWAVES (WGS / 64)         // 16
#define RPW (ROWS_WG / NWAVES)    // 4 rows per wave
#define CHUNKS (NN / 64)          // 32
#define MAX_ITER 50

// eps = 0.005; log2 domain: SCL = log2(e)/eps
constexpr float SCL       = 288.5390081777927f;
constexpr float LN2f      = 0.6931471805599453f;
constexpr float EPSf      = 0.005f;
constexpr float EPS_LOGMU = -0.03812309493079699f; // 0.005 * (-ln 2048)

#define SCOPE __HIP_MEMORY_SCOPE_AGENT

__device__ __forceinline__ float aloadf(const float* p){return __hip_atomic_load(p,__ATOMIC_RELAXED,SCOPE);}
__device__ __forceinline__ void  astoref(float* p,float v){__hip_atomic_store(p,v,__ATOMIC_RELAXED,SCOPE);}
__device__ __forceinline__ int   aloadi(const int* p){return __hip_atomic_load(p,__ATOMIC_RELAXED,SCOPE);}

__device__ __forceinline__ float fexp2(float x){return __builtin_amdgcn_exp2f(x);}
__device__ __forceinline__ float flog2(float x){return __builtin_amdgcn_logf(x);}

// monotone float<->int map so atomicMax(int) orders floats
__device__ __forceinline__ int   fkey(float x){int i=__float_as_int(x);return i>=0?i:i^0x7fffffff;}
__device__ __forceinline__ float funkey(int k){return __int_as_float(k>=0?k:k^0x7fffffff);}

__device__ __forceinline__ float wsum(float v){
  #pragma unroll
  for (int d = 32; d; d >>= 1) v += __shfl_xor(v, d, 64);
  return v;
}

// SINGLE-USE monotonic barrier: arrive = atomicAdd, release = cnt==nwg.
// No reset, no generation, no sense-reversal -> reuse/ABA race class is
// structurally impossible (r6/r7 lesson). Deadman: 131K polls (~11ms) turns
// any deadlock into a fast wrong-answer instead of a 600s timeout.
__device__ __forceinline__ void sbar(int* cnt, int nwg){
  __syncthreads();                 // all waves drain vmcnt before arrive
  if (threadIdx.x == 0) {
    asm volatile("s_waitcnt vmcnt(0)" ::: "memory");
    __hip_atomic_fetch_add(cnt, 1, __ATOMIC_RELAXED, SCOPE);
    int spins = 0;
    while (aloadi(cnt) < nwg) {
      __builtin_amdgcn_s_sleep(2);
      if (++spins > (1 << 17)) break;   // deadman
    }
  }
  __syncthreads();
}

// One-time prep: pack {x,y,z,|p|^2} for both clouds; zero the 801 single-use
// barrier counters; set the 800 max-slots to -inf; zero accum.
__global__ __launch_bounds__(256) void pack_pts(
    const float* __restrict__ pcs1, const float* __restrict__ pcs2,
    float4* __restrict__ rp1, float4* __restrict__ rp2,
    int* __restrict__ cntArr, int* __restrict__ slotMF,
    int* __restrict__ slotMG, float* __restrict__ accum)
{
  int idx = blockIdx.x * 256 + threadIdx.x;
  if (idx == 0) *accum = 0.f;
  if (idx < 801) cntArr[idx * 16] = 0;
  if (idx >= 2048 && idx < 2448) slotMF[(idx - 2048) * 16] = fkey(-3.0e38f);
  if (idx >= 4096 && idx < 4496) slotMG[(idx - 4096) * 16] = fkey(-3.0e38f);
  if (idx >= 2 * BB * NN) return;
  if (idx < BB * NN) {
    const float* s = pcs1 + 3 * (size_t)idx;
    float x = s[0], y = s[1], z = s[2];
    rp1[idx] = make_float4(x, y, z, fmaf(x, x, fmaf(y, y, z * z)));
  } else {
    int j = idx - BB * NN;
    const float* s = pcs2 + 3 * (size_t)j;
    float x = s[0], y = s[1], z = s[2];
    rp2[j] = make_float4(x, y, z, fmaf(x, x, fmaf(y, y, z * z)));
  }
}

// One half-iteration phase (r10's proven single-pass form).
// J[j].w = (pot_j - qq_j)*SCL - M ; exponent = B_r - ... <= 0 since
// M >= max_j pot_j*SCL. potIn/potOut accessed ONLY via sc1 atomics (plain
// loads could hit stale L1 across intra-kernel barriers).
__device__ __forceinline__ void half_phase(
    float4* __restrict__ J, float* __restrict__ red,
    const float4* __restrict__ RP, const float4* __restrict__ CP,
    const float* __restrict__ potIn, float* __restrict__ potOut,
    float M, int* __restrict__ slotOut,
    int b, int sub, int tid, int lane, int wv, bool zero)
{
  const size_t bo = (size_t)b * NN;
  for (int j = tid; j < NN; j += WGS) {
    float4 q = CP[bo + j];                       // plain: pack_pts output
    float pot = zero ? 0.f : aloadf(potIn + bo + j);
    J[j] = make_float4(q.x, q.y, q.z, fmaf(pot - q.w, SCL, -M));
  }
  __syncthreads();

  const int i0 = sub * ROWS_WG + wv * RPW;
  const float4 p0 = RP[bo+i0], p1 = RP[bo+i0+1], p2 = RP[bo+i0+2], p3 = RP[bo+i0+3];
  const float X0x=2.f*SCL*p0.x, X0y=2.f*SCL*p0.y, X0z=2.f*SCL*p0.z, B0=-SCL*p0.w;
  const float X1x=2.f*SCL*p1.x, X1y=2.f*SCL*p1.y, X1z=2.f*SCL*p1.z, B1=-SCL*p1.w;
  const float X2x=2.f*SCL*p2.x, X2y=2.f*SCL*p2.y, X2z=2.f*SCL*p2.z, B2=-SCL*p2.w;
  const float X3x=2.f*SCL*p3.x, X3y=2.f*SCL*p3.y, X3z=2.f*SCL*p3.z, B3=-SCL*p3.w;

  // unroll capped at 4: full unroll clusters 32 b128 loads -> spill (r1..r5)
  float s0 = 0.f, s1 = 0.f, s2 = 0.f, s3 = 0.f;
  #pragma unroll 4
  for (int k = 0; k < CHUNKS; ++k) {
    float4 q = J[k * 64 + lane];
    s0 += fexp2(fmaf(X0x, q.x, fmaf(X0y, q.y, fmaf(X0z, q.z, q.w + B0))));
    s1 += fexp2(fmaf(X1x, q.x, fmaf(X1y, q.y, fmaf(X1z, q.z, q.w + B1))));
    s2 += fexp2(fmaf(X2x, q.x, fmaf(X2y, q.y, fmaf(X2z, q.z, q.w + B2))));
    s3 += fexp2(fmaf(X3x, q.x, fmaf(X3y, q.y, fmaf(X3z, q.z, q.w + B3))));
  }
  const float S0 = wsum(s0), S1 = wsum(s1), S2 = wsum(s2), S3 = wsum(s3);
  if (lane == 0) {
    const float o0 = EPS_LOGMU - EPSf*LN2f*(M + flog2(fmaxf(S0, 1e-37f)));
    const float o1 = EPS_LOGMU - EPSf*LN2f*(M + flog2(fmaxf(S1, 1e-37f)));
    const float o2 = EPS_LOGMU - EPSf*LN2f*(M + flog2(fmaxf(S2, 1e-37f)));
    const float o3 = EPS_LOGMU - EPSf*LN2f*(M + flog2(fmaxf(S3, 1e-37f)));
    astoref(potOut + bo + i0 + 0, o0);
    astoref(potOut + bo + i0 + 1, o1);
    astoref(potOut + bo + i0 + 2, o2);
    astoref(potOut + bo + i0 + 3, o3);
    red[wv] = fmaxf(fmaxf(o0, o1), fmaxf(o2, o3));
  }
  __syncthreads();
  if (tid == 0) {
    float mx = red[0];
    #pragma unroll
    for (int w = 1; w < NWAVES; ++w) mx = fmaxf(mx, red[w]);
    atomicMax(slotOut, fkey(mx));
  }
}

__global__ __launch_bounds__(WGS) void emd_sinkhorn_fused(
    const float4* __restrict__ P1r, const float4* __restrict__ P2r,
    float* __restrict__ fArr, float* __restrict__ gArr,
    int* __restrict__ cntArr, int* __restrict__ slotMF,
    int* __restrict__ slotMG, float* __restrict__ accum,
    float* __restrict__ out)
{
  __shared__ float4 J[NN];
  __shared__ float red[NWAVES];
  const int wg = blockIdx.x, tid = threadIdx.x;
  const int b = wg / WG_PER_B, sub = wg % WG_PER_B;
  const int lane = tid & 63, wv = tid >> 6;
  const size_t bo = (size_t)b * NN;

  for (int t = 0; t < MAX_ITER; ++t) {
    // f-update: rows=pcs1, cols=pcs2+g ; M from last g-phase (0 at t=0)
    const float Mf = (t == 0) ? 0.f
        : funkey(aloadi(slotMG + ((t - 1) * 8 + b) * 16)) * SCL;
    half_phase(J, red, P1r, P2r, gArr, fArr, Mf,
               slotMF + (t * 8 + b) * 16, b, sub, tid, lane, wv, t == 0);
    sbar(cntArr + ((2 * t) * 8 + b) * 16, WG_PER_B);

    // g-update: rows=pcs2, cols=pcs1+f ; M from this f-phase
    const float Mg = funkey(aloadi(slotMF + (t * 8 + b) * 16)) * SCL;
    half_phase(J, red, P2r, P1r, fArr, gArr, Mg,
               slotMG + (t * 8 + b) * 16, b, sub, tid, lane, wv, false);
    sbar(cntArr + ((2 * t + 1) * 8 + b) * 16, WG_PER_B);
  }

  // finalize: dist_i = N * sum_j exp2((f_i+g_j-C_ij)*SCL) * C_ij
  for (int j = tid; j < NN; j += WGS) {
    float4 q = P2r[bo + j];
    J[j] = make_float4(q.x, q.y, q.z, aloadf(gArr + bo + j) * SCL);
  }
  __syncthreads();

  const int i0 = sub * ROWS_WG + wv * RPW;
  float part = 0.f;
  #pragma unroll 1
  for (int r = 0; r < RPW; ++r) {
    const int i = i0 + r;
    const float4 p = P1r[bo + i];
    const float Fi = aloadf(fArr + bo + i) * SCL;
    float a0 = 0.f, a1 = 0.f;
    #pragma unroll 2
    for (int k = 0; k < CHUNKS; k += 2) {
      float4 qa = J[k * 64 + lane];
      float4 qb = J[(k + 1) * 64 + lane];
      float dxa = p.x - qa.x, dya = p.y - qa.y, dza = p.z - qa.z;
      float ca = fmaf(dxa, dxa, fmaf(dya, dya, dza * dza));
      a0 = fmaf(fexp2(fmaf(-SCL, ca, Fi + qa.w)), ca, a0);
      float dxb = p.x - qb.x, dyb = p.y - qb.y, dzb = p.z - qb.z;
      float cb = fmaf(dxb, dxb, fmaf(dyb, dyb, dzb * dzb));
      a1 = fmaf(fexp2(fmaf(-SCL, cb, Fi + qb.w)), cb, a1);
    }
    float lacc = wsum(a0 + a1);
    if (lane == 0) part += sqrtf((float)NN * lacc + 1e-12f);
  }
  if (lane == 0) red[wv] = part;
  __syncthreads();
  if (tid == 0) {
    float s = 0.f;
    #pragma unroll
    for (int w = 0; w < NWAVES; ++w) s += red[w];
    atomicAdd(accum, s);
  }
  sbar(cntArr + 800 * 16, GRID);               // global: all partials landed
  if (wg == 0 && tid == 0) out[0] = aloadf(accum) * (1.f / 16384.f);
}

extern "C" void kernel_launch(void* const* d_in, const int* in_sizes, int n_in,
                              void* d_out, int out_size, void* d_ws, size_t ws_size,
                              hipStream_t stream) {
  const float* pcs1 = (const float*)d_in[0];
  const float* pcs2 = (const float*)d_in[1];
  float* out = (float*)d_out;
  char*  base = (char*)d_ws;
  float* fArr   = (float*)base;                    // 64KB
  float* gArr   = (float*)(base + 64 * 1024);      // 64KB
  float* accum  = (float*)(base + 128 * 1024);     // 1 float
  int*   cntArr = (int*)(base + 192 * 1024);       // 801 x 64B
  int*   slotMF = (int*)(base + 256 * 1024);       // 400 x 64B
  int*   slotMG = (int*)(base + 320 * 1024);       // 400 x 64B
  float4* P1r   = (float4*)(base + 512 * 1024);    // 256KB
  float4* P2r   = (float4*)(base + 768 * 1024);    // 256KB

  pack_pts<<<(2 * BB * NN + 255) / 256, 256, 0, stream>>>(
      pcs1, pcs2, P1r, P2r, cntArr, slotMF, slotMG, accum);

  void* args[] = { &P1r, &P2r, &fArr, &gArr, &cntArr, &slotMF, &slotMG, &accum, &out };
  hipLaunchCooperativeKernel(reinterpret_cast<void*>(emd_sinkhorn_fused),
                             dim3(GRID), dim3(WGS), args, 0, stream);
}